// Round 3
// baseline (398.292 us; speedup 1.0000x reference)
//
#include <hip/hip_runtime.h>
#include <cstddef>

// Problem constants
static constexpr int kB    = 256;   // batch
static constexpr int kS    = 196;   // att size (sequence)
static constexpr int kRNN  = 1024;  // rnn size
static constexpr int kATTH = 512;   // att hidden size
static constexpr int kQ    = 4;     // s-chunks per batch element
static constexpr int kSC   = kS / kQ;  // 49 s per chunk

// Workspace layout (floats):
//   att_h : kB*kATTH           = 131072
//   escore: kB*kS              =  50176
//   part  : kB*kQ*kRNN         = 1048576
// total ~4.7 MB fp32
static constexpr size_t kOffAttH  = 0;
static constexpr size_t kOffEsc   = kOffAttH + (size_t)kB * kATTH;
static constexpr size_t kOffPart  = kOffEsc + (size_t)kB * kS;

__device__ __forceinline__ float fast_tanh(float x) {
    x = fminf(12.0f, fmaxf(-12.0f, x));
    float e = __expf(2.0f * x);
    return __fdividef(e - 1.0f, e + 1.0f);
}

__device__ __forceinline__ float dot8t(const float4 p0, const float4 p1,
                                       const float4 ah0, const float4 ah1,
                                       const float4 wa0, const float4 wa1) {
    float r;
    r  = fast_tanh(p0.x + ah0.x) * wa0.x;
    r += fast_tanh(p0.y + ah0.y) * wa0.y;
    r += fast_tanh(p0.z + ah0.z) * wa0.z;
    r += fast_tanh(p0.w + ah0.w) * wa0.w;
    r += fast_tanh(p1.x + ah1.x) * wa1.x;
    r += fast_tanh(p1.y + ah1.y) * wa1.y;
    r += fast_tanh(p1.z + ah1.z) * wa1.z;
    r += fast_tanh(p1.w + ah1.w) * wa1.w;
    return r;
}

// ---- K1: att_h[b,:] = W h_b + bias. One block per b, 16 waves;
// wave w computes atth rows 32w..32w+31. W is L2-resident.
__global__ __launch_bounds__(1024) void k1_atth(
    const float* __restrict__ h, const float* __restrict__ w_h2att,
    const float* __restrict__ b_h2att, float* __restrict__ att_h) {
    const int b = blockIdx.x;
    const int tid = threadIdx.x;
    const int lane = tid & 63;
    const int wave = tid >> 6;

    const float* hb = &h[(size_t)b * kRNN];
    const int k0 = lane << 2;
    const float4 h0 = *(const float4*)&hb[k0];
    const float4 h1 = *(const float4*)&hb[k0 + 256];
    const float4 h2 = *(const float4*)&hb[k0 + 512];
    const float4 h3 = *(const float4*)&hb[k0 + 768];
    const int abase = wave << 5;
#pragma unroll 2
    for (int r = 0; r < 32; ++r) {
        const int a = abase + r;
        const float* wr = &w_h2att[(size_t)a * kRNN + k0];
        const float4 x0 = *(const float4*)(wr);
        const float4 x1 = *(const float4*)(wr + 256);
        const float4 x2 = *(const float4*)(wr + 512);
        const float4 x3 = *(const float4*)(wr + 768);
        float d;
        d  = x0.x * h0.x + x0.y * h0.y + x0.z * h0.z + x0.w * h0.w;
        d += x1.x * h1.x + x1.y * h1.y + x1.z * h1.z + x1.w * h1.w;
        d += x2.x * h2.x + x2.y * h2.y + x2.z * h2.z + x2.w * h2.w;
        d += x3.x * h3.x + x3.y * h3.y + x3.z * h3.z + x3.w * h3.w;
#pragma unroll
        for (int off = 32; off > 0; off >>= 1) d += __shfl_xor(d, off, 64);
        if (lane == 0) att_h[(size_t)b * kATTH + a] = d + b_h2att[a];
    }
}

// ---- K2: escore[b,s] = exp(score(b,s) + ebias), data-independent bound.
// Grid: kB*kQ blocks of 256 threads (4 waves); wave handles s = 49q + w + 4k.
__global__ __launch_bounds__(256) void k2_scores(
    const float* __restrict__ p_att, const float* __restrict__ att_h,
    const float* __restrict__ w_alpha, const float* __restrict__ b_alpha,
    float* __restrict__ escore) {
    const int b = blockIdx.x >> 2;
    const int q = blockIdx.x & 3;
    const int tid = threadIdx.x;
    const int lane = tid & 63;
    const int wave = tid >> 6;  // 0..3

    const int col = lane << 3;
    const float4 ah0 = *(const float4*)&att_h[(size_t)b * kATTH + col];
    const float4 ah1 = *(const float4*)&att_h[(size_t)b * kATTH + col + 4];
    const float4 wa0 = *(const float4*)&w_alpha[col];
    const float4 wa1 = *(const float4*)&w_alpha[col + 4];
    const float balpha = b_alpha[0];

    // score bound M = sum|w_alpha| + |b_alpha|; exponent = score + ebias <= 0
    float sw = fabsf(wa0.x) + fabsf(wa0.y) + fabsf(wa0.z) + fabsf(wa0.w) +
               fabsf(wa1.x) + fabsf(wa1.y) + fabsf(wa1.z) + fabsf(wa1.w);
#pragma unroll
    for (int off = 32; off > 0; off >>= 1) sw += __shfl_xor(sw, off, 64);
    const float ebias = balpha - (sw + fabsf(balpha));

    const float* pbase = &p_att[(size_t)b * kS * kATTH + col];
    const int send = q * kSC + kSC;
    int s = q * kSC + wave;
    float4 p0, p1;
    {
        const float* p = pbase + (size_t)s * kATTH;
        p0 = *(const float4*)p;
        p1 = *(const float4*)(p + 4);
    }
    while (true) {
        const int sn = s + 4;
        const bool more = sn < send;  // wave-uniform
        float4 np0, np1;
        if (more) {
            const float* p = pbase + (size_t)sn * kATTH;
            np0 = *(const float4*)p;
            np1 = *(const float4*)(p + 4);
        }
        float r = dot8t(p0, p1, ah0, ah1, wa0, wa1);
#pragma unroll
        for (int off = 32; off > 0; off >>= 1) r += __shfl_xor(r, off, 64);
        if (lane == 0) escore[(size_t)b * kS + s] = __expf(r + ebias);
        if (!more) break;
        s = sn;
        p0 = np0; p1 = np1;
    }
}

// ---- K3: partial weighted sums. Block (b,q): part[b][q][d] =
// sum_{s in chunk q} escore[b,s] * att_feats[b,s,d]. Pure stream, no
// cross-lane ops; unroll 7 keeps 7 independent 1KB loads in flight/wave.
__global__ __launch_bounds__(256) void k3_pv(
    const float* __restrict__ att_feats, const float* __restrict__ escore,
    float* __restrict__ part) {
    const int b = blockIdx.x >> 2;
    const int q = blockIdx.x & 3;
    const int tid = threadIdx.x;

    __shared__ float sW[kSC];
    if (tid < kSC) sW[tid] = escore[(size_t)b * kS + q * kSC + tid];
    __syncthreads();

    const float* af =
        &att_feats[((size_t)b * kS + q * kSC) * kRNN + (tid << 2)];
    float4 acc = {0.f, 0.f, 0.f, 0.f};
#pragma unroll 7
    for (int i = 0; i < kSC; ++i) {
        const float w = sW[i];
        const float4 v = *(const float4*)(af + (size_t)i * kRNN);
        acc.x += w * v.x; acc.y += w * v.y;
        acc.z += w * v.z; acc.w += w * v.w;
    }
    *(float4*)&part[((size_t)(b * kQ + q)) * kRNN + (tid << 2)] = acc;
}

// ---- K4: out[b,:] = (sum_q part[b][q][:]) / (sum_s escore[b,s])
__global__ __launch_bounds__(256) void k4_combine(
    const float* __restrict__ part, const float* __restrict__ escore,
    float* __restrict__ out) {
    const int b = blockIdx.x;
    const int tid = threadIdx.x;
    const int lane = tid & 63;
    const int wave = tid >> 6;

    __shared__ float sPart[4];
    float v = (tid < kS) ? escore[(size_t)b * kS + tid] : 0.f;
#pragma unroll
    for (int off = 32; off > 0; off >>= 1) v += __shfl_xor(v, off, 64);
    if (lane == 0) sPart[wave] = v;
    __syncthreads();
    const float inv = __fdividef(1.0f, sPart[0] + sPart[1] + sPart[2] + sPart[3]);

    const float* pb = &part[(size_t)b * kQ * kRNN + (tid << 2)];
    const float4 a0 = *(const float4*)(pb);
    const float4 a1 = *(const float4*)(pb + kRNN);
    const float4 a2 = *(const float4*)(pb + 2 * kRNN);
    const float4 a3 = *(const float4*)(pb + 3 * kRNN);
    float4 o;
    o.x = (a0.x + a1.x + a2.x + a3.x) * inv;
    o.y = (a0.y + a1.y + a2.y + a3.y) * inv;
    o.z = (a0.z + a1.z + a2.z + a3.z) * inv;
    o.w = (a0.w + a1.w + a2.w + a3.w) * inv;
    *(float4*)&out[(size_t)b * kRNN + (tid << 2)] = o;
}

extern "C" void kernel_launch(void* const* d_in, const int* in_sizes, int n_in,
                              void* d_out, int out_size, void* d_ws, size_t ws_size,
                              hipStream_t stream) {
    const float* h         = (const float*)d_in[0];
    const float* att_feats = (const float*)d_in[1];
    const float* p_att     = (const float*)d_in[2];
    const float* w_h2att   = (const float*)d_in[3];
    const float* b_h2att   = (const float*)d_in[4];
    const float* w_alpha   = (const float*)d_in[5];
    const float* b_alpha   = (const float*)d_in[6];
    float* out = (float*)d_out;

    float* ws     = (float*)d_ws;
    float* att_h  = ws + kOffAttH;   // 512 KB
    float* escore = ws + kOffEsc;    // 196 KB
    float* part   = ws + kOffPart;   // 4 MB

    k1_atth<<<kB, 1024, 0, stream>>>(h, w_h2att, b_h2att, att_h);
    k2_scores<<<kB * kQ, 256, 0, stream>>>(p_att, att_h, w_alpha, b_alpha, escore);
    k3_pv<<<kB * kQ, 256, 0, stream>>>(att_feats, escore, part);
    k4_combine<<<kB, 256, 0, stream>>>(part, escore, out);
}

// Round 4
// 387.546 us; speedup vs baseline: 1.0277x; 1.0277x over previous
//
#include <hip/hip_runtime.h>
#include <cstddef>

// Problem constants
static constexpr int kB    = 256;   // batch
static constexpr int kS    = 196;   // att size (sequence)
static constexpr int kRNN  = 1024;  // rnn size
static constexpr int kATTH = 512;   // att hidden size
static constexpr int kQ    = 4;     // s-chunks per batch element
static constexpr int kSC   = kS / kQ;  // 49 s per chunk

// Workspace layout (floats):
//   att_h : kB*kATTH   = 131072  (512 KB)
//   esum  : kB*kQ      =   1024  (per-chunk sums of exp(score+ebias))
//   part  : kB*kQ*kRNN = 1048576 (4 MB unnormalized partial outputs)
static constexpr size_t kOffAttH = 0;
static constexpr size_t kOffEsum = kOffAttH + (size_t)kB * kATTH;
static constexpr size_t kOffPart = kOffEsum + (size_t)kB * kQ;

__device__ __forceinline__ float fast_tanh(float x) {
    x = fminf(12.0f, fmaxf(-12.0f, x));
    float e = __expf(2.0f * x);
    return __fdividef(e - 1.0f, e + 1.0f);
}

__device__ __forceinline__ float dot8t(const float4 p0, const float4 p1,
                                       const float4 ah0, const float4 ah1,
                                       const float4 wa0, const float4 wa1) {
    float r;
    r  = fast_tanh(p0.x + ah0.x) * wa0.x;
    r += fast_tanh(p0.y + ah0.y) * wa0.y;
    r += fast_tanh(p0.z + ah0.z) * wa0.z;
    r += fast_tanh(p0.w + ah0.w) * wa0.w;
    r += fast_tanh(p1.x + ah1.x) * wa1.x;
    r += fast_tanh(p1.y + ah1.y) * wa1.y;
    r += fast_tanh(p1.z + ah1.z) * wa1.z;
    r += fast_tanh(p1.w + ah1.w) * wa1.w;
    return r;
}

// ---- K1: att_h[b,:] = W h_b + bias. Grid kB*4 (4 blocks/CU), 256 threads.
// Block (b, rq) computes atth rows rq*128 .. rq*128+127; wave w does 32 rows.
// W (2 MB) is L2-resident per XCD.
__global__ __launch_bounds__(256, 4) void k1_atth(
    const float* __restrict__ h, const float* __restrict__ w_h2att,
    const float* __restrict__ b_h2att, float* __restrict__ att_h) {
    const int b  = blockIdx.x >> 2;
    const int rq = blockIdx.x & 3;
    const int tid = threadIdx.x;
    const int lane = tid & 63;
    const int wave = tid >> 6;  // 0..3

    const float* hb = &h[(size_t)b * kRNN];
    const int k0 = lane << 2;  // lane covers k0, k0+256, k0+512, k0+768
    const float4 h0 = *(const float4*)&hb[k0];
    const float4 h1 = *(const float4*)&hb[k0 + 256];
    const float4 h2 = *(const float4*)&hb[k0 + 512];
    const float4 h3 = *(const float4*)&hb[k0 + 768];
    const int abase = rq * 128 + wave * 32;
#pragma unroll 2
    for (int r = 0; r < 32; ++r) {
        const int a = abase + r;
        const float* wr = &w_h2att[(size_t)a * kRNN + k0];
        const float4 x0 = *(const float4*)(wr);
        const float4 x1 = *(const float4*)(wr + 256);
        const float4 x2 = *(const float4*)(wr + 512);
        const float4 x3 = *(const float4*)(wr + 768);
        float d;
        d  = x0.x * h0.x + x0.y * h0.y + x0.z * h0.z + x0.w * h0.w;
        d += x1.x * h1.x + x1.y * h1.y + x1.z * h1.z + x1.w * h1.w;
        d += x2.x * h2.x + x2.y * h2.y + x2.z * h2.z + x2.w * h2.w;
        d += x3.x * h3.x + x3.y * h3.y + x3.z * h3.z + x3.w * h3.w;
#pragma unroll
        for (int off = 32; off > 0; off >>= 1) d += __shfl_xor(d, off, 64);
        if (lane == 0) att_h[(size_t)b * kATTH + a] = d + b_h2att[a];
    }
}

// ---- K23: fused scores + partial weighted sum for chunk (b,q).
// Phase A: e_s = exp(score_s + ebias) into LDS (data-independent bound:
//          |score| <= sum|w_alpha| + |b_alpha| since |tanh|<=1).
// Phase C: part[b][q][d] = sum_{s in chunk} e_s * att_feats[b,s,d].
// Blocks desynchronize across phases -> p_att and att_feats streams mix.
__global__ __launch_bounds__(256, 4) void k23_score_pv(
    const float* __restrict__ att_feats, const float* __restrict__ p_att,
    const float* __restrict__ att_h, const float* __restrict__ w_alpha,
    const float* __restrict__ b_alpha, float* __restrict__ esum,
    float* __restrict__ part) {
    const int b = blockIdx.x >> 2;
    const int q = blockIdx.x & 3;
    const int tid = threadIdx.x;
    const int lane = tid & 63;
    const int wave = tid >> 6;  // 0..3

    __shared__ float sE[kSC];
    __shared__ float sEw[4];

    // ---- Phase A
    const int col = lane << 3;  // 8 atth elements per lane (64*8 = 512)
    const float4 ah0 = *(const float4*)&att_h[(size_t)b * kATTH + col];
    const float4 ah1 = *(const float4*)&att_h[(size_t)b * kATTH + col + 4];
    const float4 wa0 = *(const float4*)&w_alpha[col];
    const float4 wa1 = *(const float4*)&w_alpha[col + 4];
    const float balpha = b_alpha[0];

    float sw = fabsf(wa0.x) + fabsf(wa0.y) + fabsf(wa0.z) + fabsf(wa0.w) +
               fabsf(wa1.x) + fabsf(wa1.y) + fabsf(wa1.z) + fabsf(wa1.w);
#pragma unroll
    for (int off = 32; off > 0; off >>= 1) sw += __shfl_xor(sw, off, 64);
    const float ebias = balpha - (sw + fabsf(balpha));  // score + ebias <= 0

    const float* pbase = &p_att[((size_t)b * kS + (size_t)q * kSC) * kATTH + col];
    // wave w handles local s = w, w+4, ... ; counts: wave0 -> 13, else 12.
    int s = wave;
    float4 p0 = *(const float4*)(pbase + (size_t)s * kATTH);
    float4 p1 = *(const float4*)(pbase + (size_t)s * kATTH + 4);
    const int nIter = (wave == 0) ? 13 : 12;
    float esumw = 0.f;
    for (int i = 0; i < nIter; ++i) {
        // Unconditional clamped prefetch: cannot be sunk under a guard.
        int sn = s + 4;
        sn = (sn > kSC - 1) ? (kSC - 1) : sn;
        const float4 np0 = *(const float4*)(pbase + (size_t)sn * kATTH);
        const float4 np1 = *(const float4*)(pbase + (size_t)sn * kATTH + 4);
        float r = dot8t(p0, p1, ah0, ah1, wa0, wa1);
#pragma unroll
        for (int off = 32; off > 0; off >>= 1) r += __shfl_xor(r, off, 64);
        if (lane == 0) {
            const float e = __expf(r + ebias);
            sE[s] = e;
            esumw += e;
        }
        s = sn;
        p0 = np0; p1 = np1;
    }
    if (lane == 0) sEw[wave] = esumw;
    __syncthreads();
    if (tid == 0) esum[b * kQ + q] = sEw[0] + sEw[1] + sEw[2] + sEw[3];

    // ---- Phase C: thread owns float4 d-slot tid (256*4 = 1024 = kRNN).
    const float* af =
        &att_feats[((size_t)b * kS + (size_t)q * kSC) * kRNN + (tid << 2)];
    float4 acc = {0.f, 0.f, 0.f, 0.f};
    for (int o = 0; o < 7; ++o) {
        float4 v[7];
#pragma unroll
        for (int j = 0; j < 7; ++j)
            v[j] = *(const float4*)(af + (size_t)(o * 7 + j) * kRNN);
#pragma unroll
        for (int j = 0; j < 7; ++j) {
            const float w = sE[o * 7 + j];
            acc.x += w * v[j].x; acc.y += w * v[j].y;
            acc.z += w * v[j].z; acc.w += w * v[j].w;
        }
    }
    *(float4*)&part[((size_t)(b * kQ + q)) * kRNN + (tid << 2)] = acc;
}

// ---- K4: out[b,:] = (sum_q part[b][q][:]) / (sum_q esum[b][q])
__global__ __launch_bounds__(256) void k4_combine(
    const float* __restrict__ part, const float* __restrict__ esum,
    float* __restrict__ out) {
    const int b = blockIdx.x;
    const int tid = threadIdx.x;

    const float* es = &esum[b * kQ];
    const float inv = __fdividef(1.0f, es[0] + es[1] + es[2] + es[3]);

    const float* pb = &part[(size_t)b * kQ * kRNN + (tid << 2)];
    const float4 a0 = *(const float4*)(pb);
    const float4 a1 = *(const float4*)(pb + kRNN);
    const float4 a2 = *(const float4*)(pb + 2 * kRNN);
    const float4 a3 = *(const float4*)(pb + 3 * kRNN);
    float4 o;
    o.x = (a0.x + a1.x + a2.x + a3.x) * inv;
    o.y = (a0.y + a1.y + a2.y + a3.y) * inv;
    o.z = (a0.z + a1.z + a2.z + a3.z) * inv;
    o.w = (a0.w + a1.w + a2.w + a3.w) * inv;
    *(float4*)&out[(size_t)b * kRNN + (tid << 2)] = o;
}

extern "C" void kernel_launch(void* const* d_in, const int* in_sizes, int n_in,
                              void* d_out, int out_size, void* d_ws, size_t ws_size,
                              hipStream_t stream) {
    const float* h         = (const float*)d_in[0];
    const float* att_feats = (const float*)d_in[1];
    const float* p_att     = (const float*)d_in[2];
    const float* w_h2att   = (const float*)d_in[3];
    const float* b_h2att   = (const float*)d_in[4];
    const float* w_alpha   = (const float*)d_in[5];
    const float* b_alpha   = (const float*)d_in[6];
    float* out = (float*)d_out;

    float* ws    = (float*)d_ws;
    float* att_h = ws + kOffAttH;
    float* esum  = ws + kOffEsum;
    float* part  = ws + kOffPart;

    k1_atth<<<kB * 4, 256, 0, stream>>>(h, w_h2att, b_h2att, att_h);
    k23_score_pv<<<kB * kQ, 256, 0, stream>>>(att_feats, p_att, att_h, w_alpha,
                                              b_alpha, esum, part);
    k4_combine<<<kB, 256, 0, stream>>>(part, esum, out);
}